// Round 1
// baseline (350.372 us; speedup 1.0000x reference)
//
#include <hip/hip_runtime.h>

#define LOG2E 1.44269504088896340736f

typedef short v8s __attribute__((ext_vector_type(8)));
typedef float v4f __attribute__((ext_vector_type(4)));

__device__ __forceinline__ unsigned short f2bf(float f) {
  unsigned int u = __float_as_uint(f);
  u += 0x7fffu + ((u >> 16) & 1u);   // RNE
  return (unsigned short)(u >> 16);
}

#define MFMA16(a, b, c) __builtin_amdgcn_mfma_f32_16x16x32_bf16((a), (b), (c), 0, 0, 0)

static const int BB = 8, CCH = 256, NPIX = 4096;

// ---------------- weights -> bf16 ----------------
// wqk: [64][256] rows 0..31 = Wq, rows 32..63 = Wk.  wvb: [256][256].
__global__ void wconv_kernel(const float* __restrict__ Wq, const float* __restrict__ Wk,
                             const float* __restrict__ Wv, unsigned short* __restrict__ wqk,
                             unsigned short* __restrict__ wvb) {
  int idx = blockIdx.x * 256 + threadIdx.x;
  int tot = 64 * 256 + 256 * 256;
  for (int i = idx; i < tot; i += gridDim.x * 256) {
    if (i < 64 * 256) {
      float v = (i < 32 * 256) ? Wq[i] : Wk[i - 32 * 256];
      wqk[i] = f2bf(v);
    } else {
      wvb[i - 64 * 256] = f2bf(Wv[i - 64 * 256]);
    }
  }
}

// ---------------- x [B,C,N] f32 -> xT [B,N,C] bf16 ----------------
__global__ void xpose_kernel(const float* __restrict__ x, unsigned short* __restrict__ xT) {
  __shared__ float tile[64][65];
  int bid = blockIdx.x;                 // 8 * 4 * 64
  int b = bid >> 8;
  int c0 = ((bid >> 6) & 3) * 64;
  int n0 = (bid & 63) * 64;
  int t = threadIdx.x;
  const float* xp = x + ((size_t)b * CCH + c0) * NPIX + n0;
#pragma unroll
  for (int p = 0; p < 16; ++p) {
    int cc = p * 4 + (t >> 6);
    int nn = t & 63;
    tile[cc][nn] = xp[(size_t)cc * NPIX + nn];   // coalesced along n
  }
  __syncthreads();
  unsigned short* xo = xT + ((size_t)b * NPIX + n0) * CCH + c0;
#pragma unroll
  for (int p = 0; p < 8; ++p) {
    int nn = p * 8 + (t >> 5);
    int cc = (t & 31) * 2;
    unsigned int pk = (unsigned int)f2bf(tile[cc][nn]) |
                      ((unsigned int)f2bf(tile[cc + 1][nn]) << 16);
    *(unsigned int*)(xo + (size_t)nn * CCH + cc) = pk;  // coalesced along c
  }
}

// ---------------- q/k projection: q,k [B,N,32] bf16 ----------------
// MFMA: A = xT rows n (k=c contig), B = wqk rows d (k=c contig). D: row=n, col=d.
__global__ __launch_bounds__(256, 2) void qkproj_kernel(
    const unsigned short* __restrict__ xT, const unsigned short* __restrict__ wqk,
    const float* __restrict__ bq, const float* __restrict__ bk,
    unsigned short* __restrict__ qb, unsigned short* __restrict__ kb) {
  int bid = blockIdx.x;                 // 8 * 64
  int b = bid >> 6;
  int n0 = (bid & 63) * 64;
  int w = threadIdx.x >> 6, lane = threadIdx.x & 63, g = lane >> 4, li = lane & 15;
  int nrow = n0 + 16 * w;
  v4f acc[4];
#pragma unroll
  for (int dt = 0; dt < 4; ++dt) acc[dt] = (v4f){0.f, 0.f, 0.f, 0.f};
#pragma unroll
  for (int ks = 0; ks < 8; ++ks) {
    v8s a = *(const v8s*)(xT + ((size_t)(b * NPIX + nrow + li)) * CCH + ks * 32 + g * 8);
#pragma unroll
    for (int dt = 0; dt < 4; ++dt) {
      v8s bf = *(const v8s*)(wqk + (dt * 16 + li) * 256 + ks * 32 + g * 8);
      acc[dt] = MFMA16(a, bf, acc[dt]);
    }
  }
#pragma unroll
  for (int dt = 0; dt < 4; ++dt) {
    int d = (dt & 1) * 16 + li;
    float bias = (dt < 2) ? bq[d] : bk[d];
    unsigned short* op = (dt < 2) ? qb : kb;
#pragma unroll
    for (int r = 0; r < 4; ++r) {
      int n = nrow + 4 * g + r;
      op[((size_t)(b * NPIX + n)) * 32 + d] = f2bf(acc[dt][r] + bias);
    }
  }
}

// ---------------- v projection: V [B,C,N] bf16 ----------------
// A = Wv rows c_out (k=c_in contig), B = xT rows n. D: row=c_out, col=n.
__global__ __launch_bounds__(256, 2) void vproj_kernel(
    const unsigned short* __restrict__ xT, const unsigned short* __restrict__ wvb,
    const float* __restrict__ bv, unsigned short* __restrict__ vb) {
  int bid = blockIdx.x;                 // 8 * 64
  int b = bid >> 6;
  int n0 = (bid & 63) * 64;
  int w = threadIdx.x >> 6, lane = threadIdx.x & 63, g = lane >> 4, li = lane & 15;
  v4f acc[4][4];
#pragma unroll
  for (int ct = 0; ct < 4; ++ct)
#pragma unroll
    for (int nt = 0; nt < 4; ++nt) acc[ct][nt] = (v4f){0.f, 0.f, 0.f, 0.f};
#pragma unroll
  for (int ks = 0; ks < 8; ++ks) {
    v8s xf[4];
#pragma unroll
    for (int nt = 0; nt < 4; ++nt)
      xf[nt] = *(const v8s*)(xT + ((size_t)(b * NPIX + n0 + nt * 16 + li)) * CCH + ks * 32 + g * 8);
#pragma unroll
    for (int ct = 0; ct < 4; ++ct) {
      v8s wf = *(const v8s*)(wvb + (w * 64 + ct * 16 + li) * 256 + ks * 32 + g * 8);
#pragma unroll
      for (int nt = 0; nt < 4; ++nt) acc[ct][nt] = MFMA16(wf, xf[nt], acc[ct][nt]);
    }
  }
#pragma unroll
  for (int ct = 0; ct < 4; ++ct)
#pragma unroll
    for (int r = 0; r < 4; ++r) {
      int c = w * 64 + ct * 16 + 4 * g + r;
      float bias = bv[c];
#pragma unroll
      for (int nt = 0; nt < 4; ++nt) {
        int n = n0 + nt * 16 + li;
        vb[((size_t)(b * CCH + c)) * NPIX + n] = f2bf(acc[ct][nt][r] + bias);
      }
    }
}

// ---------------- fused flash attention + residual ----------------
// Block = (b, 64 query rows). Wave w: softmax-owner of rows [16w,16w+16),
// accumulator-owner of channels [64w,64w+64) for ALL 64 rows (O^T = V P^T).
// P crosses waves via double-buffered XOR-swizzled LDS; one barrier/chunk.
#define PSWZ(il, jl) (((il) * 64 + (jl)) ^ (((il) & 7) << 3))
__global__ __launch_bounds__(256, 2) void attn_kernel(
    const unsigned short* __restrict__ qb, const unsigned short* __restrict__ kb,
    const unsigned short* __restrict__ vb, const float* __restrict__ x,
    const float* __restrict__ gamma, float* __restrict__ out) {
  __shared__ __align__(16) unsigned short pbuf[2][64 * 64];
  __shared__ float fbuf[2][64];
  __shared__ float lbuf[64];
  int bx = blockIdx.x;
  int wg = (bx & 7) * 64 + (bx >> 3);   // XCD swizzle: XCD x runs batch x (V L2 locality)
  int b = wg >> 6, it = wg & 63;
  int i0 = it * 64;
  int w = threadIdx.x >> 6, lane = threadIdx.x & 63, g = lane >> 4, li = lane & 15;

  v8s qf = *(const v8s*)(qb + ((size_t)(b * NPIX + i0 + w * 16 + li)) * 32 + g * 8);
  float m2[4], ls[4];
#pragma unroll
  for (int r = 0; r < 4; ++r) { m2[r] = -1e30f; ls[r] = 0.f; }
  v4f acc[4][4];
#pragma unroll
  for (int ct = 0; ct < 4; ++ct)
#pragma unroll
    for (int itl = 0; itl < 4; ++itl) acc[ct][itl] = (v4f){0.f, 0.f, 0.f, 0.f};
  const v4f vzero = {0.f, 0.f, 0.f, 0.f};

  for (int jc = 0; jc < 64; ++jc) {
    int j0 = jc * 64, bsel = jc & 1;
    // ---- S = Q K^T for my 16 rows (lane holds S[i=4g+r][j=li+16jt]) ----
    v4f s[4];
#pragma unroll
    for (int jt = 0; jt < 4; ++jt) {
      v8s kf = *(const v8s*)(kb + ((size_t)(b * NPIX + j0 + jt * 16 + li)) * 32 + g * 8);
      s[jt] = MFMA16(qf, kf, vzero);
    }
    // ---- online softmax in log2 domain ----
    float tmax[4];
#pragma unroll
    for (int r = 0; r < 4; ++r)
      tmax[r] = fmaxf(fmaxf(s[0][r], s[1][r]), fmaxf(s[2][r], s[3][r]));
#pragma unroll
    for (int mm = 1; mm <= 8; mm <<= 1)
#pragma unroll
      for (int r = 0; r < 4; ++r) tmax[r] = fmaxf(tmax[r], __shfl_xor(tmax[r], mm, 64));
    float m2n[4], fsc[4], rs[4];
#pragma unroll
    for (int r = 0; r < 4; ++r) {
      m2n[r] = fmaxf(m2[r], tmax[r] * LOG2E);
      fsc[r] = exp2f(m2[r] - m2n[r]);
      rs[r] = 0.f;
    }
    unsigned short pv16[4][4];
#pragma unroll
    for (int jt = 0; jt < 4; ++jt)
#pragma unroll
      for (int r = 0; r < 4; ++r) {
        float pv = exp2f(fmaf(s[jt][r], LOG2E, -m2n[r]));
        rs[r] += pv;
        pv16[jt][r] = f2bf(pv);
      }
#pragma unroll
    for (int mm = 1; mm <= 8; mm <<= 1)
#pragma unroll
      for (int r = 0; r < 4; ++r) rs[r] += __shfl_xor(rs[r], mm, 64);
#pragma unroll
    for (int r = 0; r < 4; ++r) { ls[r] = ls[r] * fsc[r] + rs[r]; m2[r] = m2n[r]; }
    // ---- publish P (bf16) + rescale factors ----
#pragma unroll
    for (int jt = 0; jt < 4; ++jt)
#pragma unroll
      for (int r = 0; r < 4; ++r) {
        int il = w * 16 + 4 * g + r, jl = jt * 16 + li;
        pbuf[bsel][PSWZ(il, jl)] = pv16[jt][r];
      }
    if (li < 4) fbuf[bsel][w * 16 + 4 * g + li] = fsc[li];
    __syncthreads();
    // ---- rescale my accumulator by all rows' factors ----
#pragma unroll
    for (int itl = 0; itl < 4; ++itl) {
      float fv = fbuf[bsel][itl * 16 + li];
#pragma unroll
      for (int ct = 0; ct < 4; ++ct) acc[ct][itl] = acc[ct][itl] * fv;
    }
    // ---- PV: O^T += V[c, j] * P^T[j, i] ----
    v8s vf[4][2];
#pragma unroll
    for (int ct = 0; ct < 4; ++ct)
#pragma unroll
      for (int sl = 0; sl < 2; ++sl)
        vf[ct][sl] = *(const v8s*)(vb + ((size_t)(b * CCH + w * 64 + ct * 16 + li)) * NPIX +
                                   j0 + sl * 32 + g * 8);
#pragma unroll
    for (int itl = 0; itl < 4; ++itl) {
      v8s pf[2];
#pragma unroll
      for (int sl = 0; sl < 2; ++sl) {
        int il = itl * 16 + li, jl = sl * 32 + g * 8;
        pf[sl] = *(const v8s*)(&pbuf[bsel][PSWZ(il, jl)]);
      }
#pragma unroll
      for (int ct = 0; ct < 4; ++ct)
#pragma unroll
        for (int sl = 0; sl < 2; ++sl) acc[ct][itl] = MFMA16(vf[ct][sl], pf[sl], acc[ct][itl]);
    }
  }
  // ---- epilogue: out = gamma * O / l + x ----
  if (li < 4) lbuf[w * 16 + 4 * g + li] = ls[li];
  __syncthreads();
  float gm = gamma[0];
#pragma unroll
  for (int itl = 0; itl < 4; ++itl) {
    float inv = gm / lbuf[itl * 16 + li];
#pragma unroll
    for (int ct = 0; ct < 4; ++ct)
#pragma unroll
      for (int r = 0; r < 4; ++r) {
        int c = w * 64 + ct * 16 + 4 * g + r;
        size_t idx = ((size_t)(b * CCH + c)) * NPIX + i0 + itl * 16 + li;
        out[idx] = acc[ct][itl][r] * inv + x[idx];
      }
  }
}

extern "C" void kernel_launch(void* const* d_in, const int* in_sizes, int n_in,
                              void* d_out, int out_size, void* d_ws, size_t ws_size,
                              hipStream_t stream) {
  const float* x = (const float*)d_in[0];
  const float* Wq = (const float*)d_in[1];
  const float* bq = (const float*)d_in[2];
  const float* Wk = (const float*)d_in[3];
  const float* bk = (const float*)d_in[4];
  const float* Wv = (const float*)d_in[5];
  const float* bv = (const float*)d_in[6];
  const float* gamma = (const float*)d_in[7];
  float* out = (float*)d_out;
  char* ws = (char*)d_ws;
  // ws layout (bytes): all 256B-aligned
  unsigned short* xT  = (unsigned short*)(ws);                    // 16 MB
  unsigned short* qb  = (unsigned short*)(ws + 16777216);         // 2 MB
  unsigned short* kb  = (unsigned short*)(ws + 18874368);         // 2 MB
  unsigned short* vb  = (unsigned short*)(ws + 20971520);         // 16 MB
  unsigned short* wqk = (unsigned short*)(ws + 37748736);         // 32 KB
  unsigned short* wvb = (unsigned short*)(ws + 37781504);         // 128 KB

  wconv_kernel<<<80, 256, 0, stream>>>(Wq, Wk, Wv, wqk, wvb);
  xpose_kernel<<<2048, 256, 0, stream>>>(x, xT);
  qkproj_kernel<<<512, 256, 0, stream>>>(xT, wqk, bq, bk, qb, kb);
  vproj_kernel<<<512, 256, 0, stream>>>(xT, wvb, bv, vb);
  attn_kernel<<<512, 256, 0, stream>>>(qb, kb, vb, x, gamma, out);
}

// Round 3
// 278.311 us; speedup vs baseline: 1.2589x; 1.2589x over previous
//
#include <hip/hip_runtime.h>

#define LOG2E 1.44269504088896340736f

typedef short v8s __attribute__((ext_vector_type(8)));
typedef float v4f __attribute__((ext_vector_type(4)));
typedef unsigned int v2u __attribute__((ext_vector_type(2)));

__device__ __forceinline__ unsigned short f2bf(float f) {
  unsigned int u = __float_as_uint(f);
  u += 0x7fffu + ((u >> 16) & 1u);   // RNE
  return (unsigned short)(u >> 16);
}

__device__ __forceinline__ unsigned int cvtpk(float lo, float hi) {
  unsigned int r;
  asm("v_cvt_pk_bf16_f32 %0, %1, %2" : "=v"(r) : "v"(lo), "v"(hi));
  return r;
}

#define MFMA16(a, b, c) __builtin_amdgcn_mfma_f32_16x16x32_bf16((a), (b), (c), 0, 0, 0)

static const int CCH = 256, NPIX = 4096;

// ---------------- weights -> bf16 ----------------
__global__ void wconv_kernel(const float* __restrict__ Wq, const float* __restrict__ Wk,
                             const float* __restrict__ Wv, unsigned short* __restrict__ wqk,
                             unsigned short* __restrict__ wvb) {
  int idx = blockIdx.x * 256 + threadIdx.x;
  int tot = 64 * 256 + 256 * 256;
  for (int i = idx; i < tot; i += gridDim.x * 256) {
    if (i < 64 * 256) {
      float v = (i < 32 * 256) ? Wq[i] : Wk[i - 32 * 256];
      wqk[i] = f2bf(v);
    } else {
      wvb[i - 64 * 256] = f2bf(Wv[i - 64 * 256]);
    }
  }
}

// ---------------- x [B,C,N] f32 -> xT [B,N,C] bf16 ----------------
__global__ void xpose_kernel(const float* __restrict__ x, unsigned short* __restrict__ xT) {
  __shared__ float tile[64][65];
  int bid = blockIdx.x;                 // 8 * 4 * 64
  int b = bid >> 8;
  int c0 = ((bid >> 6) & 3) * 64;
  int n0 = (bid & 63) * 64;
  int t = threadIdx.x;
  const float* xp = x + ((size_t)b * CCH + c0) * NPIX + n0;
#pragma unroll
  for (int p = 0; p < 16; ++p) {
    int cc = p * 4 + (t >> 6);
    int nn = t & 63;
    tile[cc][nn] = xp[(size_t)cc * NPIX + nn];
  }
  __syncthreads();
  unsigned short* xo = xT + ((size_t)b * NPIX + n0) * CCH + c0;
#pragma unroll
  for (int p = 0; p < 8; ++p) {
    int nn = p * 8 + (t >> 5);
    int cc = (t & 31) * 2;
    unsigned int pk = (unsigned int)f2bf(tile[cc][nn]) |
                      ((unsigned int)f2bf(tile[cc + 1][nn]) << 16);
    *(unsigned int*)(xo + (size_t)nn * CCH + cc) = pk;
  }
}

// ---------------- q/k projection: q,k [B,N,32] bf16 ----------------
__global__ __launch_bounds__(256, 2) void qkproj_kernel(
    const unsigned short* __restrict__ xT, const unsigned short* __restrict__ wqk,
    const float* __restrict__ bq, const float* __restrict__ bk,
    unsigned short* __restrict__ qb, unsigned short* __restrict__ kb) {
  int bid = blockIdx.x;                 // 8 * 64
  int b = bid >> 6;
  int n0 = (bid & 63) * 64;
  int w = threadIdx.x >> 6, lane = threadIdx.x & 63, g = lane >> 4, li = lane & 15;
  int nrow = n0 + 16 * w;
  v4f acc[4];
#pragma unroll
  for (int dt = 0; dt < 4; ++dt) acc[dt] = (v4f){0.f, 0.f, 0.f, 0.f};
#pragma unroll
  for (int ks = 0; ks < 8; ++ks) {
    v8s a = *(const v8s*)(xT + ((size_t)(b * NPIX + nrow + li)) * CCH + ks * 32 + g * 8);
#pragma unroll
    for (int dt = 0; dt < 4; ++dt) {
      v8s bf = *(const v8s*)(wqk + (dt * 16 + li) * 256 + ks * 32 + g * 8);
      acc[dt] = MFMA16(a, bf, acc[dt]);
    }
  }
#pragma unroll
  for (int dt = 0; dt < 4; ++dt) {
    int d = (dt & 1) * 16 + li;
    float bias = (dt < 2) ? bq[d] : bk[d];
    unsigned short* op = (dt < 2) ? qb : kb;
#pragma unroll
    for (int r = 0; r < 4; ++r) {
      int n = nrow + 4 * g + r;
      op[((size_t)(b * NPIX + n)) * 32 + d] = f2bf(acc[dt][r] + bias);
    }
  }
}

// ---------------- v projection: V [B,C,N] bf16 ----------------
__global__ __launch_bounds__(256, 2) void vproj_kernel(
    const unsigned short* __restrict__ xT, const unsigned short* __restrict__ wvb,
    const float* __restrict__ bv, unsigned short* __restrict__ vb) {
  int bid = blockIdx.x;                 // 8 * 64
  int b = bid >> 6;
  int n0 = (bid & 63) * 64;
  int w = threadIdx.x >> 6, lane = threadIdx.x & 63, g = lane >> 4, li = lane & 15;
  v4f acc[4][4];
#pragma unroll
  for (int ct = 0; ct < 4; ++ct)
#pragma unroll
    for (int nt = 0; nt < 4; ++nt) acc[ct][nt] = (v4f){0.f, 0.f, 0.f, 0.f};
#pragma unroll
  for (int ks = 0; ks < 8; ++ks) {
    v8s xf[4];
#pragma unroll
    for (int nt = 0; nt < 4; ++nt)
      xf[nt] = *(const v8s*)(xT + ((size_t)(b * NPIX + n0 + nt * 16 + li)) * CCH + ks * 32 + g * 8);
#pragma unroll
    for (int ct = 0; ct < 4; ++ct) {
      v8s wf = *(const v8s*)(wvb + (w * 64 + ct * 16 + li) * 256 + ks * 32 + g * 8);
#pragma unroll
      for (int nt = 0; nt < 4; ++nt) acc[ct][nt] = MFMA16(wf, xf[nt], acc[ct][nt]);
    }
  }
#pragma unroll
  for (int ct = 0; ct < 4; ++ct)
#pragma unroll
    for (int r = 0; r < 4; ++r) {
      int c = w * 64 + ct * 16 + 4 * g + r;
      float bias = bv[c];
#pragma unroll
      for (int nt = 0; nt < 4; ++nt) {
        int n = n0 + nt * 16 + li;
        vb[((size_t)(b * CCH + c)) * NPIX + n] = f2bf(acc[ct][nt][r] + bias);
      }
    }
}

// ---------------- fused flash attention + residual ----------------
// Swapped QK^T: s = mfma(K, Q) so lane owns row i = li (16 j's in-register).
// Wave w: softmax for rows [16w,16w+16), accumulates channels [64w,64w+64)
// for all 64 rows. P crosses waves via double-buffered swizzled LDS.
#define PSWZ(il, jl) (((il) * 64 + (jl)) ^ (((il) & 7) << 3))
__global__ __launch_bounds__(256, 2) void attn_kernel(
    const unsigned short* __restrict__ qb, const unsigned short* __restrict__ kb,
    const unsigned short* __restrict__ vb, const float* __restrict__ x,
    const float* __restrict__ gamma, float* __restrict__ out) {
  __shared__ __align__(16) unsigned short pbuf[2][64 * 64];
  __shared__ float fbuf[2][64];
  __shared__ float lbuf[64];
  int bx = blockIdx.x;
  int wg = (bx & 7) * 64 + (bx >> 3);   // XCD swizzle: batch-affine L2 for V
  int b = wg >> 6, it = wg & 63;
  int i0 = it * 64;
  int w = threadIdx.x >> 6, lane = threadIdx.x & 63, g = lane >> 4, li = lane & 15;

  v8s qf = *(const v8s*)(qb + ((size_t)(b * NPIX + i0 + w * 16 + li)) * 32 + g * 8);
  float mraw = -1e30f, ml2 = -1.44e30f, ls = 0.f;
  v4f acc[4][4];
#pragma unroll
  for (int ct = 0; ct < 4; ++ct)
#pragma unroll
    for (int itl = 0; itl < 4; ++itl) acc[ct][itl] = (v4f){0.f, 0.f, 0.f, 0.f};
  const v4f vzero = {0.f, 0.f, 0.f, 0.f};

  const unsigned short* kbase = kb + ((size_t)b * NPIX + li) * 32 + g * 8;
  const unsigned short* vb0 = vb + ((size_t)(b * CCH + w * 64 + li)) * NPIX + g * 8;
  const unsigned short* vbc[4];
#pragma unroll
  for (int ct = 0; ct < 4; ++ct) vbc[ct] = vb0 + (size_t)ct * 16 * NPIX;

  v8s kf[4];
#pragma unroll
  for (int jt = 0; jt < 4; ++jt) kf[jt] = *(const v8s*)(kbase + (size_t)(jt * 16) * 32);

  for (int jc = 0; jc < 64; ++jc) {
    int j0 = jc * 64, bsel = jc & 1;
    // ---- S^T = K Q^T: lane holds S[i = li-row][j = j0 + jt*16 + 4g + r] ----
    v4f s[4];
#pragma unroll
    for (int jt = 0; jt < 4; ++jt) s[jt] = MFMA16(kf[jt], qf, vzero);
    // ---- prefetch next K tile (consumed next iteration) ----
    int jn = (jc < 63) ? j0 + 64 : j0;
#pragma unroll
    for (int jt = 0; jt < 4; ++jt)
      kf[jt] = *(const v8s*)(kbase + (size_t)(jn + jt * 16) * 32);
    // ---- prefetch V for THIS iteration (consumed after barrier) ----
    v8s vf[4][2];
#pragma unroll
    for (int ct = 0; ct < 4; ++ct)
#pragma unroll
      for (int sl = 0; sl < 2; ++sl)
        vf[ct][sl] = *(const v8s*)(vbc[ct] + j0 + sl * 32);
    // ---- row-local softmax with defer-max (THR=8) ----
    float t0 = fmaxf(fmaxf(s[0][0], s[0][1]), fmaxf(s[0][2], s[0][3]));
    float t1 = fmaxf(fmaxf(s[1][0], s[1][1]), fmaxf(s[1][2], s[1][3]));
    float t2 = fmaxf(fmaxf(s[2][0], s[2][1]), fmaxf(s[2][2], s[2][3]));
    float t3 = fmaxf(fmaxf(s[3][0], s[3][1]), fmaxf(s[3][2], s[3][3]));
    float pmax = fmaxf(fmaxf(t0, t1), fmaxf(t2, t3));
    pmax = fmaxf(pmax, __shfl_xor(pmax, 16, 64));
    pmax = fmaxf(pmax, __shfl_xor(pmax, 32, 64));
    bool upd = pmax > mraw + 8.f;
    float nml2 = upd ? pmax * LOG2E : ml2;
    float fsc = __builtin_amdgcn_exp2f(ml2 - nml2);
    if (upd) { mraw = pmax; ml2 = nml2; }
    float p[4][4];
    float rs = 0.f;
#pragma unroll
    for (int jt = 0; jt < 4; ++jt)
#pragma unroll
      for (int r = 0; r < 4; ++r) {
        float pv = __builtin_amdgcn_exp2f(fmaf(s[jt][r], LOG2E, -nml2));
        p[jt][r] = pv;
        rs += pv;
      }
    rs += __shfl_xor(rs, 16, 64);
    rs += __shfl_xor(rs, 32, 64);
    ls = ls * fsc + rs;
    // ---- pack P to bf16, publish 4x ds_write_b64 ----
    int il = w * 16 + li;
#pragma unroll
    for (int jt = 0; jt < 4; ++jt) {
      v2u pk;
      pk.x = cvtpk(p[jt][0], p[jt][1]);
      pk.y = cvtpk(p[jt][2], p[jt][3]);
      *(v2u*)(&pbuf[bsel][PSWZ(il, jt * 16 + 4 * g)]) = pk;
    }
    if (g == 0) fbuf[bsel][il] = fsc;
    __syncthreads();
    // ---- rescale accumulator only if some row's max grew ----
    float fv[4];
#pragma unroll
    for (int itl = 0; itl < 4; ++itl) fv[itl] = fbuf[bsel][itl * 16 + li];
    int anyr = (fv[0] != 1.f) | (fv[1] != 1.f) | (fv[2] != 1.f) | (fv[3] != 1.f);
    if (__any(anyr)) {
#pragma unroll
      for (int itl = 0; itl < 4; ++itl)
#pragma unroll
        for (int ct = 0; ct < 4; ++ct) acc[ct][itl] = acc[ct][itl] * fv[itl];
    }
    // ---- PV: O^T += V[c, j] * P^T[j, i] ----
#pragma unroll
    for (int itl = 0; itl < 4; ++itl) {
      v8s pf[2];
#pragma unroll
      for (int sl = 0; sl < 2; ++sl)
        pf[sl] = *(const v8s*)(&pbuf[bsel][PSWZ(itl * 16 + li, sl * 32 + g * 8)]);
#pragma unroll
      for (int ct = 0; ct < 4; ++ct)
#pragma unroll
        for (int sl = 0; sl < 2; ++sl) acc[ct][itl] = MFMA16(vf[ct][sl], pf[sl], acc[ct][itl]);
    }
  }
  // ---- epilogue: out = gamma * O / l + x ----
  if (g == 0) lbuf[w * 16 + li] = ls;
  __syncthreads();
  float gm = gamma[0];
#pragma unroll
  for (int itl = 0; itl < 4; ++itl) {
    float inv = gm / lbuf[itl * 16 + li];
#pragma unroll
    for (int ct = 0; ct < 4; ++ct)
#pragma unroll
      for (int r = 0; r < 4; ++r) {
        int c = w * 64 + ct * 16 + 4 * g + r;
        size_t idx = ((size_t)(b * CCH + c)) * NPIX + i0 + itl * 16 + li;
        out[idx] = acc[ct][itl][r] * inv + x[idx];
      }
  }
}

extern "C" void kernel_launch(void* const* d_in, const int* in_sizes, int n_in,
                              void* d_out, int out_size, void* d_ws, size_t ws_size,
                              hipStream_t stream) {
  const float* x = (const float*)d_in[0];
  const float* Wq = (const float*)d_in[1];
  const float* bq = (const float*)d_in[2];
  const float* Wk = (const float*)d_in[3];
  const float* bk = (const float*)d_in[4];
  const float* Wv = (const float*)d_in[5];
  const float* bv = (const float*)d_in[6];
  const float* gamma = (const float*)d_in[7];
  float* out = (float*)d_out;
  char* ws = (char*)d_ws;
  unsigned short* xT  = (unsigned short*)(ws);                    // 16 MB
  unsigned short* qb  = (unsigned short*)(ws + 16777216);         // 2 MB
  unsigned short* kb  = (unsigned short*)(ws + 18874368);         // 2 MB
  unsigned short* vb  = (unsigned short*)(ws + 20971520);         // 16 MB
  unsigned short* wqk = (unsigned short*)(ws + 37748736);         // 32 KB
  unsigned short* wvb = (unsigned short*)(ws + 37781504);         // 128 KB

  wconv_kernel<<<80, 256, 0, stream>>>(Wq, Wk, Wv, wqk, wvb);
  xpose_kernel<<<2048, 256, 0, stream>>>(x, xT);
  qkproj_kernel<<<512, 256, 0, stream>>>(xT, wqk, bq, bk, qb, kb);
  vproj_kernel<<<512, 256, 0, stream>>>(xT, wvb, bv, vb);
  attn_kernel<<<512, 256, 0, stream>>>(qb, kb, vb, x, gamma, out);
}

// Round 4
// 274.659 us; speedup vs baseline: 1.2757x; 1.0133x over previous
//
#include <hip/hip_runtime.h>

#define LOG2E 1.44269504088896340736f

typedef short v8s __attribute__((ext_vector_type(8)));
typedef float v4f __attribute__((ext_vector_type(4)));
typedef unsigned int v2u __attribute__((ext_vector_type(2)));

__device__ __forceinline__ unsigned short f2bf(float f) {
  unsigned int u = __float_as_uint(f);
  u += 0x7fffu + ((u >> 16) & 1u);   // RNE
  return (unsigned short)(u >> 16);
}

__device__ __forceinline__ unsigned int cvtpk(float lo, float hi) {
  unsigned int r;
  asm("v_cvt_pk_bf16_f32 %0, %1, %2" : "=v"(r) : "v"(lo), "v"(hi));
  return r;
}

#define MFMA16(a, b, c) __builtin_amdgcn_mfma_f32_16x16x32_bf16((a), (b), (c), 0, 0, 0)

static const int CCH = 256, NPIX = 4096;

// ---------------- weights -> bf16 ----------------
__global__ void wconv_kernel(const float* __restrict__ Wq, const float* __restrict__ Wk,
                             const float* __restrict__ Wv, unsigned short* __restrict__ wqk,
                             unsigned short* __restrict__ wvb) {
  int idx = blockIdx.x * 256 + threadIdx.x;
  int tot = 64 * 256 + 256 * 256;
  for (int i = idx; i < tot; i += gridDim.x * 256) {
    if (i < 64 * 256) {
      float v = (i < 32 * 256) ? Wq[i] : Wk[i - 32 * 256];
      wqk[i] = f2bf(v);
    } else {
      wvb[i - 64 * 256] = f2bf(Wv[i - 64 * 256]);
    }
  }
}

// ---------------- x [B,C,N] f32 -> xT [B,N,C] bf16 ----------------
__global__ void xpose_kernel(const float* __restrict__ x, unsigned short* __restrict__ xT) {
  __shared__ float tile[64][65];
  int bid = blockIdx.x;                 // 8 * 4 * 64
  int b = bid >> 8;
  int c0 = ((bid >> 6) & 3) * 64;
  int n0 = (bid & 63) * 64;
  int t = threadIdx.x;
  const float* xp = x + ((size_t)b * CCH + c0) * NPIX + n0;
#pragma unroll
  for (int p = 0; p < 16; ++p) {
    int cc = p * 4 + (t >> 6);
    int nn = t & 63;
    tile[cc][nn] = xp[(size_t)cc * NPIX + nn];
  }
  __syncthreads();
  unsigned short* xo = xT + ((size_t)b * NPIX + n0) * CCH + c0;
#pragma unroll
  for (int p = 0; p < 8; ++p) {
    int nn = p * 8 + (t >> 5);
    int cc = (t & 31) * 2;
    unsigned int pk = (unsigned int)f2bf(tile[cc][nn]) |
                      ((unsigned int)f2bf(tile[cc + 1][nn]) << 16);
    *(unsigned int*)(xo + (size_t)nn * CCH + cc) = pk;
  }
}

// ---------------- q/k projection: q,k [B,N,32] bf16 ----------------
__global__ __launch_bounds__(256, 2) void qkproj_kernel(
    const unsigned short* __restrict__ xT, const unsigned short* __restrict__ wqk,
    const float* __restrict__ bq, const float* __restrict__ bk,
    unsigned short* __restrict__ qb, unsigned short* __restrict__ kb) {
  int bid = blockIdx.x;                 // 8 * 64
  int b = bid >> 6;
  int n0 = (bid & 63) * 64;
  int w = threadIdx.x >> 6, lane = threadIdx.x & 63, g = lane >> 4, li = lane & 15;
  int nrow = n0 + 16 * w;
  v4f acc[4];
#pragma unroll
  for (int dt = 0; dt < 4; ++dt) acc[dt] = (v4f){0.f, 0.f, 0.f, 0.f};
#pragma unroll
  for (int ks = 0; ks < 8; ++ks) {
    v8s a = *(const v8s*)(xT + ((size_t)(b * NPIX + nrow + li)) * CCH + ks * 32 + g * 8);
#pragma unroll
    for (int dt = 0; dt < 4; ++dt) {
      v8s bf = *(const v8s*)(wqk + (dt * 16 + li) * 256 + ks * 32 + g * 8);
      acc[dt] = MFMA16(a, bf, acc[dt]);
    }
  }
#pragma unroll
  for (int dt = 0; dt < 4; ++dt) {
    int d = (dt & 1) * 16 + li;
    float bias = (dt < 2) ? bq[d] : bk[d];
    unsigned short* op = (dt < 2) ? qb : kb;
#pragma unroll
    for (int r = 0; r < 4; ++r) {
      int n = nrow + 4 * g + r;
      op[((size_t)(b * NPIX + n)) * 32 + d] = f2bf(acc[dt][r] + bias);
    }
  }
}

// ---------------- v projection: V [B,C,N] bf16 ----------------
__global__ __launch_bounds__(256, 2) void vproj_kernel(
    const unsigned short* __restrict__ xT, const unsigned short* __restrict__ wvb,
    const float* __restrict__ bv, unsigned short* __restrict__ vb) {
  int bid = blockIdx.x;                 // 8 * 64
  int b = bid >> 6;
  int n0 = (bid & 63) * 64;
  int w = threadIdx.x >> 6, lane = threadIdx.x & 63, g = lane >> 4, li = lane & 15;
  v4f acc[4][4];
#pragma unroll
  for (int ct = 0; ct < 4; ++ct)
#pragma unroll
    for (int nt = 0; nt < 4; ++nt) acc[ct][nt] = (v4f){0.f, 0.f, 0.f, 0.f};
#pragma unroll
  for (int ks = 0; ks < 8; ++ks) {
    v8s xf[4];
#pragma unroll
    for (int nt = 0; nt < 4; ++nt)
      xf[nt] = *(const v8s*)(xT + ((size_t)(b * NPIX + n0 + nt * 16 + li)) * CCH + ks * 32 + g * 8);
#pragma unroll
    for (int ct = 0; ct < 4; ++ct) {
      v8s wf = *(const v8s*)(wvb + (w * 64 + ct * 16 + li) * 256 + ks * 32 + g * 8);
#pragma unroll
      for (int nt = 0; nt < 4; ++nt) acc[ct][nt] = MFMA16(wf, xf[nt], acc[ct][nt]);
    }
  }
#pragma unroll
  for (int ct = 0; ct < 4; ++ct)
#pragma unroll
    for (int r = 0; r < 4; ++r) {
      int c = w * 64 + ct * 16 + 4 * g + r;
      float bias = bv[c];
#pragma unroll
      for (int nt = 0; nt < 4; ++nt) {
        int n = n0 + nt * 16 + li;
        vb[((size_t)(b * CCH + c)) * NPIX + n] = f2bf(acc[ct][nt][r] + bias);
      }
    }
}

// ---------------- fused flash attention + residual ----------------
// 8 waves / 512 threads. Waves 0-3 (producers): swapped QK^T (mfma(K,Q)) +
// row-local softmax for rows [16w,16w+16), publish P/fsc via double-buffered
// swizzled LDS. All 8 waves: PV for a 32-channel slice (c in [32w,32w+32)).
// Consumers (waves 4-7) wait at the barrier while producers compute -> their
// SIMD slots absorb producer latency (role-split overlap via occupancy).
#define PSWZ(il, jl) (((il) * 64 + (jl)) ^ (((il) & 7) << 3))
__global__ __launch_bounds__(512, 4) void attn_kernel(
    const unsigned short* __restrict__ qb, const unsigned short* __restrict__ kb,
    const unsigned short* __restrict__ vb, const float* __restrict__ x,
    const float* __restrict__ gamma, float* __restrict__ out) {
  __shared__ __align__(16) unsigned short pbuf[2][64 * 64];
  __shared__ float fbuf[2][64];
  __shared__ float lbuf[64];
  int bx = blockIdx.x;
  int wg = (bx & 7) * 64 + (bx >> 3);   // XCD swizzle: batch-affine L2 for K/V
  int b = wg >> 6, it = wg & 63;
  int i0 = it * 64;
  int w = threadIdx.x >> 6, lane = threadIdx.x & 63, g = lane >> 4, li = lane & 15;
  bool prod = (w < 4);

  float mraw = -1e30f, ml2 = -1.44e30f, ls = 0.f;
  v4f acc[2][4];
#pragma unroll
  for (int ct = 0; ct < 2; ++ct)
#pragma unroll
    for (int itl = 0; itl < 4; ++itl) acc[ct][itl] = (v4f){0.f, 0.f, 0.f, 0.f};
  const v4f vzero = {0.f, 0.f, 0.f, 0.f};

  // PV operands: wave w owns channels [32w, 32w+32)
  const unsigned short* vb0 = vb + ((size_t)(b * CCH + w * 32 + li)) * NPIX + g * 8;
  const unsigned short* vbc[2];
#pragma unroll
  for (int ct = 0; ct < 2; ++ct) vbc[ct] = vb0 + (size_t)ct * 16 * NPIX;

  const unsigned short* kbase = kb + ((size_t)b * NPIX + li) * 32 + g * 8;
  v8s qf = {0, 0, 0, 0, 0, 0, 0, 0};
  v8s kf[4];
  if (prod) {
    qf = *(const v8s*)(qb + ((size_t)(b * NPIX + i0 + w * 16 + li)) * 32 + g * 8);
#pragma unroll
    for (int jt = 0; jt < 4; ++jt) kf[jt] = *(const v8s*)(kbase + (size_t)(jt * 16) * 32);
  }

  for (int jc = 0; jc < 64; ++jc) {
    int j0 = jc * 64, bsel = jc & 1;
    // ---- V prefetch (all waves; consumed after barrier) ----
    v8s vf[2][2];
#pragma unroll
    for (int ct = 0; ct < 2; ++ct)
#pragma unroll
      for (int sl = 0; sl < 2; ++sl)
        vf[ct][sl] = *(const v8s*)(vbc[ct] + j0 + sl * 32);
    if (prod) {
      // ---- S^T = K Q^T: lane holds S[i = li][j = j0 + jt*16 + 4g + r] ----
      v4f s[4];
#pragma unroll
      for (int jt = 0; jt < 4; ++jt) s[jt] = MFMA16(kf[jt], qf, vzero);
      // ---- prefetch next K tile ----
      int jn = (jc < 63) ? j0 + 64 : j0;
#pragma unroll
      for (int jt = 0; jt < 4; ++jt)
        kf[jt] = *(const v8s*)(kbase + (size_t)(jn + jt * 16) * 32);
      // ---- row-local softmax with defer-max (THR=8) ----
      float t0 = fmaxf(fmaxf(s[0][0], s[0][1]), fmaxf(s[0][2], s[0][3]));
      float t1 = fmaxf(fmaxf(s[1][0], s[1][1]), fmaxf(s[1][2], s[1][3]));
      float t2 = fmaxf(fmaxf(s[2][0], s[2][1]), fmaxf(s[2][2], s[2][3]));
      float t3 = fmaxf(fmaxf(s[3][0], s[3][1]), fmaxf(s[3][2], s[3][3]));
      float pmax = fmaxf(fmaxf(t0, t1), fmaxf(t2, t3));
      pmax = fmaxf(pmax, __shfl_xor(pmax, 16, 64));
      pmax = fmaxf(pmax, __shfl_xor(pmax, 32, 64));
      bool upd = pmax > mraw + 8.f;
      float nml2 = upd ? pmax * LOG2E : ml2;
      float fsc = __builtin_amdgcn_exp2f(ml2 - nml2);
      if (upd) { mraw = pmax; ml2 = nml2; }
      int il = w * 16 + li;
      float rs = 0.f;
#pragma unroll
      for (int jt = 0; jt < 4; ++jt) {
        float p0 = __builtin_amdgcn_exp2f(fmaf(s[jt][0], LOG2E, -nml2));
        float p1 = __builtin_amdgcn_exp2f(fmaf(s[jt][1], LOG2E, -nml2));
        float p2 = __builtin_amdgcn_exp2f(fmaf(s[jt][2], LOG2E, -nml2));
        float p3 = __builtin_amdgcn_exp2f(fmaf(s[jt][3], LOG2E, -nml2));
        rs += (p0 + p1) + (p2 + p3);
        v2u pk;
        pk.x = cvtpk(p0, p1);
        pk.y = cvtpk(p2, p3);
        *(v2u*)(&pbuf[bsel][PSWZ(il, jt * 16 + 4 * g)]) = pk;
      }
      rs += __shfl_xor(rs, 16, 64);
      rs += __shfl_xor(rs, 32, 64);
      ls = ls * fsc + rs;
      if (g == 0) fbuf[bsel][il] = fsc;
    }
    __syncthreads();
    // ---- rescale accumulator only if some row's max grew ----
    float fv[4];
#pragma unroll
    for (int itl = 0; itl < 4; ++itl) fv[itl] = fbuf[bsel][itl * 16 + li];
    int anyr = (fv[0] != 1.f) | (fv[1] != 1.f) | (fv[2] != 1.f) | (fv[3] != 1.f);
    if (__any(anyr)) {
#pragma unroll
      for (int itl = 0; itl < 4; ++itl)
#pragma unroll
        for (int ct = 0; ct < 2; ++ct) acc[ct][itl] = acc[ct][itl] * fv[itl];
    }
    // ---- PV: O^T += V[c, j] * P^T[j, i] ----
#pragma unroll
    for (int itl = 0; itl < 4; ++itl) {
      v8s pf[2];
#pragma unroll
      for (int sl = 0; sl < 2; ++sl)
        pf[sl] = *(const v8s*)(&pbuf[bsel][PSWZ(itl * 16 + li, sl * 32 + g * 8)]);
#pragma unroll
      for (int ct = 0; ct < 2; ++ct)
#pragma unroll
        for (int sl = 0; sl < 2; ++sl) acc[ct][itl] = MFMA16(vf[ct][sl], pf[sl], acc[ct][itl]);
    }
  }
  // ---- epilogue: out = gamma * O / l + x ----
  if (prod && g == 0) lbuf[w * 16 + li] = ls;
  __syncthreads();
  float gm = gamma[0];
#pragma unroll
  for (int itl = 0; itl < 4; ++itl) {
    float inv = gm / lbuf[itl * 16 + li];
#pragma unroll
    for (int ct = 0; ct < 2; ++ct)
#pragma unroll
      for (int r = 0; r < 4; ++r) {
        int c = w * 32 + ct * 16 + 4 * g + r;
        size_t idx = ((size_t)(b * CCH + c)) * NPIX + i0 + itl * 16 + li;
        out[idx] = acc[ct][itl][r] * inv + x[idx];
      }
  }
}

extern "C" void kernel_launch(void* const* d_in, const int* in_sizes, int n_in,
                              void* d_out, int out_size, void* d_ws, size_t ws_size,
                              hipStream_t stream) {
  const float* x = (const float*)d_in[0];
  const float* Wq = (const float*)d_in[1];
  const float* bq = (const float*)d_in[2];
  const float* Wk = (const float*)d_in[3];
  const float* bk = (const float*)d_in[4];
  const float* Wv = (const float*)d_in[5];
  const float* bv = (const float*)d_in[6];
  const float* gamma = (const float*)d_in[7];
  float* out = (float*)d_out;
  char* ws = (char*)d_ws;
  unsigned short* xT  = (unsigned short*)(ws);                    // 16 MB
  unsigned short* qb  = (unsigned short*)(ws + 16777216);         // 2 MB
  unsigned short* kb  = (unsigned short*)(ws + 18874368);         // 2 MB
  unsigned short* vb  = (unsigned short*)(ws + 20971520);         // 16 MB
  unsigned short* wqk = (unsigned short*)(ws + 37748736);         // 32 KB
  unsigned short* wvb = (unsigned short*)(ws + 37781504);         // 128 KB

  wconv_kernel<<<80, 256, 0, stream>>>(Wq, Wk, Wv, wqk, wvb);
  xpose_kernel<<<2048, 256, 0, stream>>>(x, xT);
  qkproj_kernel<<<512, 256, 0, stream>>>(xT, wqk, bq, bk, qb, kb);
  vproj_kernel<<<512, 256, 0, stream>>>(xT, wvb, bv, vb);
  attn_kernel<<<512, 512, 0, stream>>>(qb, kb, vb, x, gamma, out);
}